// Round 1
// baseline (113.741 us; speedup 1.0000x reference)
//
#include <hip/hip_runtime.h>
#include <math.h>

#define NB 8
#define HW 28
#define PP 784   // 28*28

// ---------------- K1: 1x1 adder conv 256->64 ----------------
// grid (13, 4, 8), block 256. Thread: 4 contiguous px, 1 co. w staged in LDS.
__global__ __launch_bounds__(256) void k1_adder1x1(const float* __restrict__ x,
                                                   const float* __restrict__ w1,
                                                   float* __restrict__ h1) {
    __shared__ float ws[16][257];   // pad to spread banks
    const int n      = blockIdx.z;
    const int cobase = blockIdx.y * 16;
    const int pxg    = threadIdx.x & 15;
    const int co_l   = threadIdx.x >> 4;
    const int px0    = blockIdx.x * 64 + pxg * 4;

    // stage w1[cobase..cobase+15][0..255]
    #pragma unroll
    for (int c = 0; c < 16; ++c)
        ws[c][threadIdx.x] = w1[(size_t)(cobase + c) * 256 + threadIdx.x];
    __syncthreads();

    if (px0 >= PP) return;

    float a0 = 0.f, a1 = 0.f, a2 = 0.f, a3 = 0.f;
    const float* xp = x + (size_t)n * 256 * PP + px0;
    #pragma unroll 8
    for (int ci = 0; ci < 256; ++ci) {
        float4 xv = *(const float4*)(xp + (size_t)ci * PP);
        float  w  = ws[co_l][ci];
        a0 += fabsf(xv.x - w);
        a1 += fabsf(xv.y - w);
        a2 += fabsf(xv.z - w);
        a3 += fabsf(xv.w - w);
    }
    float4 o = make_float4(-a0, -a1, -a2, -a3);
    *(float4*)(h1 + ((size_t)n * 64 + cobase + co_l) * PP + px0) = o;
}

// ---------------- K2: depthwise 3x3 adder (PEG) + BN1 + ReLU ----------------
// thread per output element. grid 1568, block 256.
__global__ __launch_bounds__(256) void k2_peg_bn_relu(const float* __restrict__ h1,
                                                      const float* __restrict__ wp,
                                                      const float* __restrict__ g1,
                                                      const float* __restrict__ b1,
                                                      const float* __restrict__ m1,
                                                      const float* __restrict__ v1,
                                                      float* __restrict__ h2r) {
    int o = blockIdx.x * 256 + threadIdx.x;           // < 8*64*784
    int xx = o % HW;
    int t  = o / HW;
    int y  = t % HW;  t /= HW;
    int c  = t % 64;
    int n  = t / 64;

    const float* base = h1 + ((size_t)(n * 64 + c)) * PP;
    const float* wc   = wp + c * 9;
    float acc = 0.f;
    #pragma unroll
    for (int kh = 0; kh < 3; ++kh) {
        int yy = y + kh - 1;
        bool rv = (yy >= 0) & (yy < HW);
        #pragma unroll
        for (int kw = 0; kw < 3; ++kw) {
            int xc = xx + kw - 1;
            float v = (rv && xc >= 0 && xc < HW) ? base[yy * HW + xc] : 0.f;
            acc += fabsf(v - wc[kh * 3 + kw]);
        }
    }
    float inv = g1[c] * rsqrtf(v1[c] + 1e-5f);
    float bb  = b1[c] - m1[c] * inv;
    float r   = -acc * inv + bb;
    h2r[o] = fmaxf(r, 0.f);
}

// ---------------- K3: 3x3 adder conv 64->64 (pad 1) + BN2 + ReLU ----------------
// grid (28, 4, 8), block 128. Thread: 4 contiguous px in row y, 1 co.
// Sliding 6-float window shares loads across the 3 kw taps.
__global__ __launch_bounds__(128) void k3_adder3x3_bn_relu(const float* __restrict__ h2r,
                                                           const float* __restrict__ w2,
                                                           const float* __restrict__ g2,
                                                           const float* __restrict__ b2,
                                                           const float* __restrict__ m2,
                                                           const float* __restrict__ v2,
                                                           float* __restrict__ h3r) {
    __shared__ float ws[16][577];  // [co_l][ci*9+tap], stride 577 spreads banks
    const int y      = blockIdx.x;        // 0..27
    const int cobase = blockIdx.y * 16;
    const int n      = blockIdx.z;
    const int co_l   = threadIdx.x & 15;
    const int grp    = threadIdx.x >> 4;  // 0..7 (7 active for compute)

    for (int c = 0; c < 16; ++c)
        for (int r = threadIdx.x; r < 576; r += 128)
            ws[c][r] = w2[(size_t)(cobase + c) * 576 + r];
    __syncthreads();

    if (grp >= 7) return;
    const int px0 = grp * 4;
    const int co  = cobase + co_l;

    float acc0 = 0.f, acc1 = 0.f, acc2 = 0.f, acc3 = 0.f;
    const float* nbase = h2r + (size_t)n * 64 * PP;
    for (int ci = 0; ci < 64; ++ci) {
        const float* base = nbase + (size_t)ci * PP;
        const float* wr   = &ws[co_l][ci * 9];
        #pragma unroll
        for (int kh = 0; kh < 3; ++kh) {
            int yy = y + kh - 1;
            bool rv = (yy >= 0) & (yy < HW);
            float seg[6];
            #pragma unroll
            for (int j = 0; j < 6; ++j) {
                int xc = px0 - 1 + j;                  // per-thread constant cols
                seg[j] = (rv && xc >= 0 && xc < HW) ? base[yy * HW + xc] : 0.f;
            }
            #pragma unroll
            for (int kw = 0; kw < 3; ++kw) {
                float w = wr[kh * 3 + kw];
                acc0 += fabsf(seg[kw + 0] - w);
                acc1 += fabsf(seg[kw + 1] - w);
                acc2 += fabsf(seg[kw + 2] - w);
                acc3 += fabsf(seg[kw + 3] - w);
            }
        }
    }
    float inv = g2[co] * rsqrtf(v2[co] + 1e-5f);
    float bb  = b2[co] - m2[co] * inv;
    float4 o;
    o.x = fmaxf(-acc0 * inv + bb, 0.f);
    o.y = fmaxf(-acc1 * inv + bb, 0.f);
    o.z = fmaxf(-acc2 * inv + bb, 0.f);
    o.w = fmaxf(-acc3 * inv + bb, 0.f);
    *(float4*)(h3r + ((size_t)n * 64 + co) * PP + y * HW + px0) = o;
}

// ---------------- K6: 1x1 adder conv 64->256 + BN3 + residual + ReLU ----------------
// grid (13, 16, 8), block 256. Thread: 4 contiguous px, 1 co.
__global__ __launch_bounds__(256) void k6_adder1x1_bn_res_relu(const float* __restrict__ h3r,
                                                               const float* __restrict__ w3,
                                                               const float* __restrict__ x,
                                                               const float* __restrict__ g3,
                                                               const float* __restrict__ b3,
                                                               const float* __restrict__ m3,
                                                               const float* __restrict__ v3,
                                                               float* __restrict__ out) {
    __shared__ float ws[16][65];
    const int n      = blockIdx.z;
    const int cobase = blockIdx.y * 16;
    const int pxg    = threadIdx.x & 15;
    const int co_l   = threadIdx.x >> 4;
    const int px0    = blockIdx.x * 64 + pxg * 4;

    #pragma unroll
    for (int k = 0; k < 4; ++k) {
        int idx = k * 256 + threadIdx.x;
        int c = idx >> 6, r = idx & 63;
        ws[c][r] = w3[(size_t)cobase * 64 + idx];
    }
    __syncthreads();

    if (px0 >= PP) return;

    float a0 = 0.f, a1 = 0.f, a2 = 0.f, a3 = 0.f;
    const float* hp = h3r + (size_t)n * 64 * PP + px0;
    #pragma unroll 8
    for (int ci = 0; ci < 64; ++ci) {
        float4 xv = *(const float4*)(hp + (size_t)ci * PP);
        float  w  = ws[co_l][ci];
        a0 += fabsf(xv.x - w);
        a1 += fabsf(xv.y - w);
        a2 += fabsf(xv.z - w);
        a3 += fabsf(xv.w - w);
    }
    const int co = cobase + co_l;
    float inv = g3[co] * rsqrtf(v3[co] + 1e-5f);
    float bb  = b3[co] - m3[co] * inv;
    size_t obase = ((size_t)n * 256 + co) * PP + px0;
    float4 res = *(const float4*)(x + obase);
    float4 o;
    o.x = fmaxf(-a0 * inv + bb + res.x, 0.f);
    o.y = fmaxf(-a1 * inv + bb + res.y, 0.f);
    o.z = fmaxf(-a2 * inv + bb + res.z, 0.f);
    o.w = fmaxf(-a3 * inv + bb + res.w, 0.f);
    *(float4*)(out + obase) = o;
}

extern "C" void kernel_launch(void* const* d_in, const int* in_sizes, int n_in,
                              void* d_out, int out_size, void* d_ws, size_t ws_size,
                              hipStream_t stream) {
    const float* x  = (const float*)d_in[0];
    const float* w1 = (const float*)d_in[1];
    const float* wp = (const float*)d_in[2];
    const float* w2 = (const float*)d_in[3];
    const float* w3 = (const float*)d_in[4];
    const float* g1 = (const float*)d_in[5];
    const float* b1 = (const float*)d_in[6];
    const float* m1 = (const float*)d_in[7];
    const float* v1 = (const float*)d_in[8];
    const float* g2 = (const float*)d_in[9];
    const float* b2 = (const float*)d_in[10];
    const float* m2 = (const float*)d_in[11];
    const float* v2 = (const float*)d_in[12];
    const float* g3 = (const float*)d_in[13];
    const float* b3 = (const float*)d_in[14];
    const float* m3 = (const float*)d_in[15];
    const float* v3 = (const float*)d_in[16];
    float* out = (float*)d_out;

    float* h1  = (float*)d_ws;            // 8*64*784 = 401408 floats
    float* h2r = h1 + 401408;
    float* h3r = h2r + 401408;

    k1_adder1x1<<<dim3(13, 4, 8), 256, 0, stream>>>(x, w1, h1);
    k2_peg_bn_relu<<<dim3(1568), 256, 0, stream>>>(h1, wp, g1, b1, m1, v1, h2r);
    k3_adder3x3_bn_relu<<<dim3(28, 4, 8), 128, 0, stream>>>(h2r, w2, g2, b2, m2, v2, h3r);
    k6_adder1x1_bn_res_relu<<<dim3(13, 16, 8), 256, 0, stream>>>(h3r, w3, x, g3, b3, m3, v3, out);
}